// Round 15
// baseline (142.074 us; speedup 1.0000x reference)
//
#include <hip/hip_runtime.h>
#include <cstdint>

typedef __attribute__((ext_vector_type(8))) short bf16x8;    // 8 bf16 = 4 VGPRs
typedef __attribute__((ext_vector_type(16))) float f32x16;   // 32x32 MFMA C/D
typedef __attribute__((ext_vector_type(4))) float f4;
typedef __attribute__((ext_vector_type(8))) unsigned short u16x8;
typedef unsigned short u16;

// JOURNAL:
// R9: 32x32x16 MFMA. R11/R12: ws aliasing abort -> fixed.
// R13 FAILED: TN 64->128 without pipeline: 47.2us (residency 2.25 blk/CU).
// R14: 2-phase dbuf + counted vmcnt: GEMMs ~41us. R16: +XCD swz = 137.7.
// R17-R21: single-buf/256^2-2ph/deep-ring x2/atomic epilogue — all
//      neutral-to-worse. ~42us of dur = harness ws re-poison (fixed cost).
// R22: revert verified 138.3. Exposed-latency wall; nothing saturated.
// R23 WIN=134.9: 4->8 waves/block (512 thr, 16 waves/CU) at identical
//      structure — wave-level hiding (m114) is the one responsive lever.
// R24 FAILED CORRECTNESS: TN->64 24-waves variant; unlocalized. Abandoned.
// R25 infra fail. R26 verified R23 again: 134.1 (BANKED best, 2x verified).
// R27 (this round): same lever to the HW cap: 1024-thr blocks (16 waves) x
//      2 blk/CU = 32 waves/CU (chip max; LDS 2x64KB<=160, thr 2048=cap).
//      Pure re-division of the R23 template: same tile/BK/swizzle/skeleton/
//      epilogue; per-wave acc[1] (16 VGPR -> expect <=64 total = m69 knee);
//      stage 1 A-chunk + 1 B-chunk per thread -> vmcnt(2). gemm3 grid stays
//      512; reduce4 -> 256x1024 mirrored 4x4 decode. Predict GEMMs -2-3us
//      each, total ~128-131; null => lever saturated, R23 final (banked);
//      fail => localizes R24 bug to fine-decomposition, R23 final (banked).

__device__ __forceinline__ u16 f2bf(float f) {
  uint32_t u = __builtin_bit_cast(uint32_t, f);
  u += 0x7fffu + ((u >> 16) & 1u);          // round-to-nearest-even
  return (u16)(u >> 16);
}

__device__ __forceinline__ float bf2f(u16 h) {
  return __builtin_bit_cast(float, (uint32_t)h << 16);
}

__device__ __forceinline__ void async_cp16(const void* g, void* l) {
  __builtin_amdgcn_global_load_lds(
      (const __attribute__((address_space(1))) uint32_t*)g,
      (__attribute__((address_space(3))) uint32_t*)l, 16, 0, 0);
}

// cast x | features | prototypes -> contiguous bf16 region in ws (8 elem/thread)
__global__ __launch_bounds__(256) void cast3(
    const float* __restrict__ x, const float* __restrict__ f,
    const float* __restrict__ p, u16* __restrict__ dst,
    int n1, int n2, int n3) {
  int i = (blockIdx.x * 256 + threadIdx.x) * 8;
  const float* src;
  int local;
  if (i < n1) { src = x; local = i; }
  else if (i < n1 + n2) { src = f; local = i - n1; }
  else if (i < n1 + n2 + n3) { src = p; local = i - n1 - n2; }
  else return;
  f4 a = *(const f4*)(src + local);
  f4 b = *(const f4*)(src + local + 4);
  u16x8 o;
  o[0] = f2bf(a.x); o[1] = f2bf(a.y); o[2] = f2bf(a.z); o[3] = f2bf(a.w);
  o[4] = f2bf(b.x); o[5] = f2bf(b.y); o[6] = f2bf(b.z); o[7] = f2bf(b.w);
  *(u16x8*)(dst + i) = o;
}

// ---- 2-phase pipelined main loop (TM=128, TN=128, BK=64), 1024 threads ----
// C += A @ B^T with 32x32x16 MFMA. Same 16B-chunk XOR swizzle as R16/R23
// (8 chunks/row: balanced over all 8 LDS bank-groups).
// 16 waves in 4x4 grid: wave covers 32 rows x 32 cols = acc[1] (16 VGPR).
// Double-buffered LDS; next tile's 2 global_load_lds issued BEFORE compute,
// then counted s_waitcnt vmcnt(2) + raw s_barrier (T3/T4 minimum recipe).

__device__ __forceinline__ void stage_tile1k(
    const u16* __restrict__ A, const u16* __restrict__ B, int K,
    int k0, int tid, u16* L) {
  const int wave = tid >> 6;
  {                                    // A: 128 rows x 8 chunks = 1024 = 1/thread
    int c = tid;                       // chunk index = LDS position
    int row = c >> 3, pc = c & 7;
    int gc = pc ^ (row & 7);           // which global 16B chunk lands here
    async_cp16(A + (size_t)row * K + (k0 + gc * 8),
               &L[(wave * 64) * 8]);
  }
  {                                    // B: 128 rows x 8 chunks = 1024 = 1/thread
    int c = tid;
    int row = c >> 3, pc = c & 7;
    int gc = pc ^ (row & 7);
    async_cp16(B + (size_t)row * K + (k0 + gc * 8),
               &L[8192 + (wave * 64) * 8]);
  }
}

__device__ __forceinline__ void compute_tile1k(
    const u16* L, int lane, int wrow, int wcol, f32x16& acc) {
  #pragma unroll
  for (int s = 0; s < 4; ++s) {        // 4 k-steps of K=16
    const int h = s * 2 + (lane >> 5); // 16B chunk along K this lane needs
    const int ra = wrow * 32 + (lane & 31);
    const int rb = wcol * 32 + (lane & 31);
    bf16x8 afr = *(const bf16x8*)&L[(ra * 8 + (h ^ (ra & 7))) * 8];
    bf16x8 bfr = *(const bf16x8*)&L[8192 + (rb * 8 + (h ^ (rb & 7))) * 8];
    acc = __builtin_amdgcn_mfma_f32_32x32x16_bf16(afr, bfr, acc, 0, 0, 0);
  }
}

__device__ __forceinline__ void mainloop1k(
    const u16* __restrict__ A, const u16* __restrict__ B, int K,
    int kbeg, int kend, int tid, u16* lds, f32x16& acc) {
  constexpr int BK = 64;
  constexpr int BUF = 16384;           // u16 per LDS buffer (32 KiB)
  const int lane = tid & 63;
  const int wave = tid >> 6;
  const int wrow = wave >> 2, wcol = wave & 3;   // 4x4 wave grid

  stage_tile1k(A, B, K, kbeg, tid, lds); // prologue: tile 0 -> buf 0
  int cur = 0;
  for (int k0 = kbeg; k0 < kend; k0 += BK) {
    if (k0 + BK < kend) {
      // issue next tile (2 loads/thread), then wait ONLY the 2 older loads.
      stage_tile1k(A, B, K, k0 + BK, tid, lds + (cur ^ 1) * BUF);
      asm volatile("s_waitcnt vmcnt(2)" ::: "memory");
    } else {
      asm volatile("s_waitcnt vmcnt(0)" ::: "memory");
    }
    __builtin_amdgcn_s_barrier();      // all waves: current buffer complete
    compute_tile1k(lds + cur * BUF, lane, wrow, wcol, acc);
    __builtin_amdgcn_s_barrier();      // all waves done reading before next
    cur ^= 1;                          // iter overwrites this buffer
  }
}

// 32x32 C/D mapping (m74/m101 verified): col = lane&31,
// row = (reg&3) + 8*(reg>>2) + 4*(lane>>5), reg in [0,16).

// ---- GEMM1+GEMM2 merged: [x; proto](4608 x 1024) @ feat^T, tile 128x128 ----
// 1D grid 576, 1024 threads; XCD-supertile decode (9x8 panel per XCD).
// x-rows  -> Acat[row, f]=xf*relu(xf), Acat[row, 2048+f]=1-relu(xf)
// p-rows  -> Bcat[row, f]=th*c-al*(1-pres), Bcat[row, 2048+f]=-be*c
// Epilogue: LDS transpose (stride 136 u16) -> 128B-coalesced u16x8 stores.
__global__ __launch_bounds__(1024) void gemm12(
    const u16* __restrict__ xb, const u16* __restrict__ pb,
    const u16* __restrict__ fb, u16* __restrict__ Acat, u16* __restrict__ Bcat,
    const float* __restrict__ alpha, const float* __restrict__ beta,
    const float* __restrict__ theta) {
  constexpr int TM = 128, K = 1024, N = 2048;
  constexpr int TSTRIDE = 136;           // u16; 272B rows = 17*16B aligned
  __shared__ u16 lds[32768];             // 64 KiB: 2 mainloop bufs; transpose reuses

  const int tid = threadIdx.x;
  const int lane = tid & 63;
  const int wave = tid >> 6;
  const int wrow = wave >> 2, wcol = wave & 3;   // 4x4 wave grid

  // XCD-aware supertile decode (bijective: 576 = 8 * 72, panels 9x8)
  const int bid = blockIdx.x;
  const int xcd = bid & 7, slot = bid >> 3;        // xcd 0..7, slot 0..71
  const int xt = (xcd & 3) * 9 + (slot >> 3);      // 0..35
  const int yt = (xcd >> 2) * 8 + (slot & 7);      // 0..15

  const int bm_all = xt * TM;
  const int bn = yt * 128;
  const bool is_x = bm_all < 4096;       // block purely x or proto (4096%128==0)
  const u16* A = is_x ? xb + (size_t)bm_all * K : pb + (size_t)(bm_all - 4096) * K;
  const u16* B = fb + (size_t)bn * K;

  f32x16 acc = {};
  mainloop1k(A, B, K, 0, K, tid, lds, acc);

  float th = 0.f, al = 0.f, be = 0.f;
  if (!is_x) { th = theta[0]; al = alpha[0]; be = beta[0]; }
  u16* dst = is_x ? Acat : Bcat;
  const int rowbase = is_x ? bm_all : bm_all - 4096;
  const int rquad = 4 * (lane >> 5);
  const int cl = wcol * 32 + (lane & 31);

  #pragma unroll
  for (int half = 0; half < 2; ++half) {
    __syncthreads();   // protect lds reuse (mainloop end / previous half's reads)
    #pragma unroll
    for (int r = 0; r < 16; ++r) {
      const int rl = wrow * 32 + (r & 3) + 8 * (r >> 2) + rquad;
      float v = acc[r];
      float pres = v > 0.f ? v : 0.f;
      float o;
      if (is_x) o = half == 0 ? v * pres : 1.f - pres;
      else {
        float cc = v * pres;
        o = half == 0 ? th * cc - al * (1.f - pres) : -be * cc;
      }
      lds[rl * TSTRIDE + cl] = f2bf(o);
    }
    __syncthreads();
    #pragma unroll
    for (int v = 0; v < 2; ++v) {
      const int rl = v * 64 + (tid >> 4);
      const int c8 = (tid & 15) * 8;
      u16x8 vec = *(const u16x8*)&lds[rl * TSTRIDE + c8];
      *(u16x8*)&dst[(size_t)(rowbase + rl) * (2 * N) + bn + c8 + half * N] = vec;
    }
  }
}

// ---- GEMM3 split-K: part[z] = Acat @ Bcat^T partial (bf16), tile 128x128 ----
// 1D grid 512, 1024 threads (2 blk/CU = 32 waves/CU); XCD-supertile decode:
// XCD k = bid%8 owns 16x * 4y * 1z (z = k/2, xh = k%2). KSPLIT=4.
// Partials bf16 thread-linear: tile = 16384 u16; chunk q = h (0..1), 8192 each.
__global__ __launch_bounds__(1024) void gemm3(
    const u16* __restrict__ Acat, const u16* __restrict__ Bcat,
    u16* __restrict__ part) {
  constexpr int TM = 128, TN = 128, K = 4096, KSPLIT = 4;
  __shared__ u16 lds[32768];             // 64 KiB: 2 mainloop bufs

  const int tid = threadIdx.x;

  // XCD-aware supertile decode (bijective: 512 = 8 * 64, panels 16x4x1)
  const int bid = blockIdx.x;
  const int xcd = bid & 7, slot = bid >> 3;        // xcd 0..7, slot 0..63
  const int bz = xcd >> 1;                         // 0..3 (K quarter)
  const int bxt = (xcd & 1) * 16 + (slot >> 2);    // 0..31
  const int byt = slot & 3;                        // 0..3

  const int bm = bxt * TM;
  const int bn = byt * TN;
  const int kbeg = bz * (K / KSPLIT);
  const int kend = kbeg + (K / KSPLIT);

  f32x16 acc = {};
  mainloop1k(Acat + (size_t)bm * K, Bcat + (size_t)bn * K, K, kbeg, kend,
             tid, lds, acc);

  const size_t pbase = ((size_t)bz * 128 + byt * 32 + bxt) * 16384;
  #pragma unroll
  for (int h = 0; h < 2; ++h) {
    u16x8 o;
    #pragma unroll
    for (int e = 0; e < 8; ++e) o[e] = f2bf(acc[h * 8 + e]);
    *(u16x8*)&part[pbase + (size_t)h * 8192 + tid * 8] = o;
  }
}

// ---- reduce bf16 partials over z=0..4, scatter fp32 to out ----
// 256 blocks x 1024 thr: one q-chunk per block (tileId = bid>>1, q = bid&1).
// Mirrors gemm3 map: q = h; reg = q*8+e; 4x4 wave grid:
// row = bm + (wave>>2)*32 + (reg&3)+8*(reg>>2)+4*(lane>>5);
// col = bn + (wave&3)*32 + (lane&31).
__global__ __launch_bounds__(1024) void reduce4(
    const u16* __restrict__ part, float* __restrict__ out) {
  constexpr int N = 512;
  const int tid = threadIdx.x;
  const int lane = tid & 63;
  const int wave = tid >> 6;
  const int wrow = wave >> 2, wcol = wave & 3;
  const int tileId = blockIdx.x >> 1;      // 0..127 = byt*32+bxt
  const int q = blockIdx.x & 1;
  const int bm = (tileId & 31) * 128;
  const int bn = (tileId >> 5) * 128;

  float v[8] = {};
  #pragma unroll
  for (int z = 0; z < 4; ++z) {
    u16x8 u = *(const u16x8*)&part[((size_t)z * 128 + tileId) * 16384 +
                                   (size_t)q * 8192 + tid * 8];
    #pragma unroll
    for (int e = 0; e < 8; ++e) v[e] += bf2f(u[e]);
  }
  const int gc = bn + wcol * 32 + (lane & 31);
  const int grb = bm + wrow * 32 + 4 * (lane >> 5);
  #pragma unroll
  for (int e = 0; e < 8; ++e) {
    const int reg = q * 8 + e;
    out[(size_t)(grb + (reg & 3) + 8 * (reg >> 2)) * N + gc] = v[e];
  }
}

extern "C" void kernel_launch(void* const* d_in, const int* in_sizes, int n_in,
                              void* d_out, int out_size, void* d_ws, size_t ws_size,
                              hipStream_t stream) {
  const float* x     = (const float*)d_in[0];
  const float* feat  = (const float*)d_in[1];
  const float* proto = (const float*)d_in[2];
  const float* alpha = (const float*)d_in[3];
  const float* beta  = (const float*)d_in[4];
  const float* theta = (const float*)d_in[5];
  float* out = (float*)d_out;

  constexpr int Bb = 4096, Ii = 1024, Pp = 512, Ff = 2048;

  // ws layout (NO aliasing — R12 defensive change): casts | Acat | Bcat | part.
  // Total ~88 MB of the 256 MiB workspace.
  char* ws = (char*)d_ws;
  u16* xb   = (u16*)ws;                               // 8.4 MB
  u16* fb   = xb + (size_t)Bb * Ii;                   // 4.2 MB
  u16* pb   = fb + (size_t)Ff * Ii;                   // 1.0 MB
  size_t r0 = 33554432;                               // 32 MiB region0 (casts)
  u16* Acat = (u16*)(ws + r0);                        // 33.6 MB
  u16* Bcat = Acat + (size_t)Bb * 2 * Ff;             // 4.2 MB
  u16* part = Bcat + (size_t)Pp * 2 * Ff;             // 16.8 MB (dedicated)

  const int n1 = Bb * Ii, n2 = Ff * Ii, n3 = Pp * Ii;
  cast3<<<((n1 + n2 + n3) / 8 + 255) / 256, 256, 0, stream>>>(
      x, feat, proto, xb, n1, n2, n3);

  // merged GEMM1+GEMM2: M=4608, N=2048; 1D grid 576 x 1024 threads
  gemm12<<<576, 1024, 0, stream>>>(xb, pb, fb, Acat, Bcat, alpha, beta, theta);

  // GEMM3: 4096x512, K=4096 split 4 ways; 1D grid 512 x 1024 threads
  gemm3<<<512, 1024, 0, stream>>>(Acat, Bcat, part);

  // reduce z=0..4 -> out (2 q-chunks per tile, one per block)
  reduce4<<<256, 1024, 0, stream>>>(part, out);
}

// Round 16
// 136.798 us; speedup vs baseline: 1.0386x; 1.0386x over previous
//
#include <hip/hip_runtime.h>
#include <cstdint>

typedef __attribute__((ext_vector_type(8))) short bf16x8;    // 8 bf16 = 4 VGPRs
typedef __attribute__((ext_vector_type(16))) float f32x16;   // 32x32 MFMA C/D
typedef __attribute__((ext_vector_type(4))) float f4;
typedef __attribute__((ext_vector_type(8))) unsigned short u16x8;
typedef unsigned short u16;

// JOURNAL (final):
// R9: 32x32x16 MFMA. R11/R12: ws aliasing abort -> fixed.
// R13 FAILED: TN 64->128 without pipeline: 47.2us (residency 2.25 blk/CU).
// R14: 2-phase dbuf + counted vmcnt: GEMMs ~41us. R16: +XCD swz = 137.7.
// R17-R21: single-buf/256^2-2ph/deep-ring x2/atomic epilogue — all
//      neutral-to-worse. ~42us of dur = harness ws re-poison (fixed cost).
// R22: revert verified 138.3. Exposed-latency wall; nothing saturated.
// R23 WIN=134.9: 4->8 waves/block (512 thr, 16 waves/CU). R26 re-verified
//      134.1 (BANKED best). Wave-level hiding (m114) = the responsive lever.
// R24 FAILED CORRECTNESS: TN->64 24-waves variant; unlocalized. Abandoned.
// R27 REGRESSED (142.1): 1024-thr / 32 waves/CU — per-wave work too small
//      (4 MFMA/tile vs fixed barrier cost; 16 lockstep waves). Wave curve
//      mapped: 8w=41us, 16w=39us (OPT), 32w=43us per GEMM.
// R28 (final): resubmit banked best (R23/R26 verbatim). Not roofline
//      (~19% dense peak; hipBLASLt-class schedules would do better), but
//      one-shot-per-round schedule space is exhausted; 134.1 is 2x verified.

__device__ __forceinline__ u16 f2bf(float f) {
  uint32_t u = __builtin_bit_cast(uint32_t, f);
  u += 0x7fffu + ((u >> 16) & 1u);          // round-to-nearest-even
  return (u16)(u >> 16);
}

__device__ __forceinline__ float bf2f(u16 h) {
  return __builtin_bit_cast(float, (uint32_t)h << 16);
}

__device__ __forceinline__ void async_cp16(const void* g, void* l) {
  __builtin_amdgcn_global_load_lds(
      (const __attribute__((address_space(1))) uint32_t*)g,
      (__attribute__((address_space(3))) uint32_t*)l, 16, 0, 0);
}

// cast x | features | prototypes -> contiguous bf16 region in ws (8 elem/thread)
__global__ __launch_bounds__(256) void cast3(
    const float* __restrict__ x, const float* __restrict__ f,
    const float* __restrict__ p, u16* __restrict__ dst,
    int n1, int n2, int n3) {
  int i = (blockIdx.x * 256 + threadIdx.x) * 8;
  const float* src;
  int local;
  if (i < n1) { src = x; local = i; }
  else if (i < n1 + n2) { src = f; local = i - n1; }
  else if (i < n1 + n2 + n3) { src = p; local = i - n1 - n2; }
  else return;
  f4 a = *(const f4*)(src + local);
  f4 b = *(const f4*)(src + local + 4);
  u16x8 o;
  o[0] = f2bf(a.x); o[1] = f2bf(a.y); o[2] = f2bf(a.z); o[3] = f2bf(a.w);
  o[4] = f2bf(b.x); o[5] = f2bf(b.y); o[6] = f2bf(b.z); o[7] = f2bf(b.w);
  *(u16x8*)(dst + i) = o;
}

// ---- 2-phase pipelined main loop (TM=128, TN=128, BK=64), 512 threads ----
// C += A @ B^T with 32x32x16 MFMA. 16B-chunk XOR swizzle (8 chunks/row:
// balanced over all 8 LDS bank-groups — do NOT shrink).
// 8 waves in 4x2 grid: wave covers 32 rows x 128 cols = 1x2 acc tiles.
// Double-buffered LDS; next tile's 4 global_load_lds issued BEFORE compute,
// then counted s_waitcnt vmcnt(4) + raw s_barrier (T3/T4 minimum recipe).

__device__ __forceinline__ void stage_tile512(
    const u16* __restrict__ A, const u16* __restrict__ B, int K,
    int k0, int tid, u16* L) {
  const int wave = tid >> 6;
  #pragma unroll
  for (int it = 0; it < 2; ++it) {     // A: 128 rows x 8 chunks = 1024
    int c = it * 512 + tid;            // chunk index = LDS position
    int row = c >> 3, pc = c & 7;
    int gc = pc ^ (row & 7);           // which global 16B chunk lands here
    async_cp16(A + (size_t)row * K + (k0 + gc * 8),
               &L[(it * 512 + wave * 64) * 8]);
  }
  #pragma unroll
  for (int it = 0; it < 2; ++it) {     // B: 128 rows x 8 chunks
    int c = it * 512 + tid;
    int row = c >> 3, pc = c & 7;
    int gc = pc ^ (row & 7);
    async_cp16(B + (size_t)row * K + (k0 + gc * 8),
               &L[8192 + (it * 512 + wave * 64) * 8]);
  }
}

__device__ __forceinline__ void compute_tile512(
    const u16* L, int lane, int wrow, int wcol, f32x16 (&acc)[2]) {
  #pragma unroll
  for (int s = 0; s < 4; ++s) {        // 4 k-steps of K=16
    const int h = s * 2 + (lane >> 5); // 16B chunk along K this lane needs
    const int ra = wrow * 32 + (lane & 31);
    bf16x8 afr = *(const bf16x8*)&L[(ra * 8 + (h ^ (ra & 7))) * 8];
    #pragma unroll
    for (int j = 0; j < 2; ++j) {
      const int rb = wcol * 64 + j * 32 + (lane & 31);
      bf16x8 bfr = *(const bf16x8*)&L[8192 + (rb * 8 + (h ^ (rb & 7))) * 8];
      acc[j] = __builtin_amdgcn_mfma_f32_32x32x16_bf16(afr, bfr, acc[j], 0, 0, 0);
    }
  }
}

__device__ __forceinline__ void mainloop512(
    const u16* __restrict__ A, const u16* __restrict__ B, int K,
    int kbeg, int kend, int tid, u16* lds, f32x16 (&acc)[2]) {
  constexpr int BK = 64;
  constexpr int BUF = 16384;           // u16 per LDS buffer (32 KiB)
  const int lane = tid & 63;
  const int wave = tid >> 6;
  const int wrow = wave >> 1, wcol = wave & 1;

  stage_tile512(A, B, K, kbeg, tid, lds); // prologue: tile 0 -> buf 0
  int cur = 0;
  for (int k0 = kbeg; k0 < kend; k0 += BK) {
    if (k0 + BK < kend) {
      // issue next tile (4 loads/thread), then wait ONLY the 4 older loads.
      stage_tile512(A, B, K, k0 + BK, tid, lds + (cur ^ 1) * BUF);
      asm volatile("s_waitcnt vmcnt(4)" ::: "memory");
    } else {
      asm volatile("s_waitcnt vmcnt(0)" ::: "memory");
    }
    __builtin_amdgcn_s_barrier();      // all waves: current buffer complete
    compute_tile512(lds + cur * BUF, lane, wrow, wcol, acc);
    __builtin_amdgcn_s_barrier();      // all waves done reading before next
    cur ^= 1;                          // iter overwrites this buffer
  }
}

// 32x32 C/D mapping (m74/m101 verified): col = lane&31,
// row = (reg&3) + 8*(reg>>2) + 4*(lane>>5), reg in [0,16).

// ---- GEMM1+GEMM2 merged: [x; proto](4608 x 1024) @ feat^T, tile 128x128 ----
// 1D grid 576, 512 threads; XCD-supertile decode (9x8 panel per XCD).
// x-rows  -> Acat[row, f]=xf*relu(xf), Acat[row, 2048+f]=1-relu(xf)
// p-rows  -> Bcat[row, f]=th*c-al*(1-pres), Bcat[row, 2048+f]=-be*c
// Epilogue: LDS transpose (stride 136 u16) -> 128B-coalesced u16x8 stores.
__global__ __launch_bounds__(512) void gemm12(
    const u16* __restrict__ xb, const u16* __restrict__ pb,
    const u16* __restrict__ fb, u16* __restrict__ Acat, u16* __restrict__ Bcat,
    const float* __restrict__ alpha, const float* __restrict__ beta,
    const float* __restrict__ theta) {
  constexpr int TM = 128, K = 1024, N = 2048;
  constexpr int TSTRIDE = 136;           // u16; 272B rows = 17*16B aligned
  __shared__ u16 lds[32768];             // 64 KiB: 2 mainloop bufs; transpose reuses

  const int tid = threadIdx.x;
  const int lane = tid & 63;
  const int wave = tid >> 6;
  const int wrow = wave >> 1, wcol = wave & 1;   // 4x2 wave grid

  // XCD-aware supertile decode (bijective: 576 = 8 * 72, panels 9x8)
  const int bid = blockIdx.x;
  const int xcd = bid & 7, slot = bid >> 3;        // xcd 0..7, slot 0..71
  const int xt = (xcd & 3) * 9 + (slot >> 3);      // 0..35
  const int yt = (xcd >> 2) * 8 + (slot & 7);      // 0..15

  const int bm_all = xt * TM;
  const int bn = yt * 128;
  const bool is_x = bm_all < 4096;       // block purely x or proto (4096%128==0)
  const u16* A = is_x ? xb + (size_t)bm_all * K : pb + (size_t)(bm_all - 4096) * K;
  const u16* B = fb + (size_t)bn * K;

  f32x16 acc[2] = {};
  mainloop512(A, B, K, 0, K, tid, lds, acc);

  float th = 0.f, al = 0.f, be = 0.f;
  if (!is_x) { th = theta[0]; al = alpha[0]; be = beta[0]; }
  u16* dst = is_x ? Acat : Bcat;
  const int rowbase = is_x ? bm_all : bm_all - 4096;
  const int rquad = 4 * (lane >> 5);

  #pragma unroll
  for (int half = 0; half < 2; ++half) {
    __syncthreads();   // protect lds reuse (mainloop end / previous half's reads)
    #pragma unroll
    for (int j = 0; j < 2; ++j) {
      const int cl = wcol * 64 + j * 32 + (lane & 31);
      #pragma unroll
      for (int r = 0; r < 16; ++r) {
        const int rl = wrow * 32 + (r & 3) + 8 * (r >> 2) + rquad;
        float v = acc[j][r];
        float pres = v > 0.f ? v : 0.f;
        float o;
        if (is_x) o = half == 0 ? v * pres : 1.f - pres;
        else {
          float cc = v * pres;
          o = half == 0 ? th * cc - al * (1.f - pres) : -be * cc;
        }
        lds[rl * TSTRIDE + cl] = f2bf(o);
      }
    }
    __syncthreads();
    #pragma unroll
    for (int v = 0; v < 4; ++v) {
      const int rl = v * 32 + (tid >> 4);
      const int c8 = (tid & 15) * 8;
      u16x8 vec = *(const u16x8*)&lds[rl * TSTRIDE + c8];
      *(u16x8*)&dst[(size_t)(rowbase + rl) * (2 * N) + bn + c8 + half * N] = vec;
    }
  }
}

// ---- GEMM3 split-K: part[z] = Acat @ Bcat^T partial (bf16), tile 128x128 ----
// 1D grid 512, 512 threads; XCD-supertile decode: XCD k = bid%8 owns
// 16x * 4y * 1z (z = k/2, xh = k%2). KSPLIT=4. Partials bf16 thread-linear:
// tile = 16384 u16; chunk q = j*2 + h (0..3), 4096 u16 each.
__global__ __launch_bounds__(512) void gemm3(
    const u16* __restrict__ Acat, const u16* __restrict__ Bcat,
    u16* __restrict__ part) {
  constexpr int TM = 128, TN = 128, K = 4096, KSPLIT = 4;
  __shared__ u16 lds[32768];             // 64 KiB: 2 mainloop bufs

  const int tid = threadIdx.x;

  // XCD-aware supertile decode (bijective: 512 = 8 * 64, panels 16x4x1)
  const int bid = blockIdx.x;
  const int xcd = bid & 7, slot = bid >> 3;        // xcd 0..7, slot 0..63
  const int bz = xcd >> 1;                         // 0..3 (K quarter)
  const int bxt = (xcd & 1) * 16 + (slot >> 2);    // 0..31
  const int byt = slot & 3;                        // 0..3

  const int bm = bxt * TM;
  const int bn = byt * TN;
  const int kbeg = bz * (K / KSPLIT);
  const int kend = kbeg + (K / KSPLIT);

  f32x16 acc[2] = {};
  mainloop512(Acat + (size_t)bm * K, Bcat + (size_t)bn * K, K, kbeg, kend,
              tid, lds, acc);

  const size_t pbase = ((size_t)bz * 128 + byt * 32 + bxt) * 16384;
  #pragma unroll
  for (int j = 0; j < 2; ++j)
    #pragma unroll
    for (int h = 0; h < 2; ++h) {
      u16x8 o;
      #pragma unroll
      for (int e = 0; e < 8; ++e) o[e] = f2bf(acc[j][h * 8 + e]);
      *(u16x8*)&part[pbase + (size_t)(j * 2 + h) * 4096 + tid * 8] = o;
    }
}

// ---- reduce bf16 partials over z=0..4, scatter fp32 to out ----
// 512 blocks x 512 thr: one q-chunk per block (tileId = bid>>2, q = bid&3).
// Mirrors gemm3 map: q = j*2+h; reg = h*8+e; 4x2 wave grid:
// row = bm + (wave>>1)*32 + (reg&3)+8*(reg>>2)+4*(lane>>5);
// col = bn + (wave&1)*64 + j*32 + (lane&31).
__global__ __launch_bounds__(512) void reduce4(
    const u16* __restrict__ part, float* __restrict__ out) {
  constexpr int N = 512;
  const int tid = threadIdx.x;
  const int lane = tid & 63;
  const int wave = tid >> 6;
  const int wrow = wave >> 1, wcol = wave & 1;
  const int tileId = blockIdx.x >> 2;      // 0..127 = byt*32+bxt
  const int q = blockIdx.x & 3;
  const int bm = (tileId & 31) * 128;
  const int bn = (tileId >> 5) * 128;

  float v[8] = {};
  #pragma unroll
  for (int z = 0; z < 4; ++z) {
    u16x8 u = *(const u16x8*)&part[((size_t)z * 128 + tileId) * 16384 +
                                   (size_t)q * 4096 + tid * 8];
    #pragma unroll
    for (int e = 0; e < 8; ++e) v[e] += bf2f(u[e]);
  }
  const int j = q >> 1, h = q & 1;
  const int gc = bn + wcol * 64 + j * 32 + (lane & 31);
  const int grb = bm + wrow * 32 + 4 * (lane >> 5);
  #pragma unroll
  for (int e = 0; e < 8; ++e) {
    const int reg = h * 8 + e;
    out[(size_t)(grb + (reg & 3) + 8 * (reg >> 2)) * N + gc] = v[e];
  }
}

extern "C" void kernel_launch(void* const* d_in, const int* in_sizes, int n_in,
                              void* d_out, int out_size, void* d_ws, size_t ws_size,
                              hipStream_t stream) {
  const float* x     = (const float*)d_in[0];
  const float* feat  = (const float*)d_in[1];
  const float* proto = (const float*)d_in[2];
  const float* alpha = (const float*)d_in[3];
  const float* beta  = (const float*)d_in[4];
  const float* theta = (const float*)d_in[5];
  float* out = (float*)d_out;

  constexpr int Bb = 4096, Ii = 1024, Pp = 512, Ff = 2048;

  // ws layout (NO aliasing — R12 defensive change): casts | Acat | Bcat | part.
  // Total ~88 MB of the 256 MiB workspace.
  char* ws = (char*)d_ws;
  u16* xb   = (u16*)ws;                               // 8.4 MB
  u16* fb   = xb + (size_t)Bb * Ii;                   // 4.2 MB
  u16* pb   = fb + (size_t)Ff * Ii;                   // 1.0 MB
  size_t r0 = 33554432;                               // 32 MiB region0 (casts)
  u16* Acat = (u16*)(ws + r0);                        // 33.6 MB
  u16* Bcat = Acat + (size_t)Bb * 2 * Ff;             // 4.2 MB
  u16* part = Bcat + (size_t)Pp * 2 * Ff;             // 16.8 MB (dedicated)

  const int n1 = Bb * Ii, n2 = Ff * Ii, n3 = Pp * Ii;
  cast3<<<((n1 + n2 + n3) / 8 + 255) / 256, 256, 0, stream>>>(
      x, feat, proto, xb, n1, n2, n3);

  // merged GEMM1+GEMM2: M=4608, N=2048; 1D grid 576 x 512 threads
  gemm12<<<576, 512, 0, stream>>>(xb, pb, fb, Acat, Bcat, alpha, beta, theta);

  // GEMM3: 4096x512, K=4096 split 4 ways; 1D grid 512 x 512 threads
  gemm3<<<512, 512, 0, stream>>>(Acat, Bcat, part);

  // reduce z=0..4 -> out (4 q-chunks per tile, one per block)
  reduce4<<<512, 512, 0, stream>>>(part, out);
}